// Round 1
// baseline (308.534 us; speedup 1.0000x reference)
//
#include <hip/hip_runtime.h>

// snnTorch Leaky recurrence, reset_mechanism='subtract':
//   reset_t = H(mem_{t-1} - uth)   == spk_{t-1}  (key reuse: one compare/step)
//   mem_t   = beta*mem_{t-1} + x_t - reset_t*uth
//   spk_t   = H(mem_t - uth)
// N=8192 neurons (independent), T=4000 (sequential). Memory-streaming bound:
// 262 MB total traffic, floor ~42 us @ 6.3 TB/s.
//
// Numerics: MUST match reference rounding order ((0.95*mem + x) - r) with NO
// fma contraction — a 1-ulp difference near the threshold flips a spike and
// the absmax threshold (2e-2) tolerates zero flips. Hence __f*_rn intrinsics.

namespace {

constexpr int T_LEN = 4000;
constexpr int N_NEU = 8192;
constexpr int CHV   = 10;                  // float4s per chunk = 40 floats
constexpr int NCH   = T_LEN / (CHV * 4);   // 100 chunks (even — clean ping-pong)

__device__ __forceinline__ float step1(float x, float& mem, float& r) {
    // mem = (0.95f*mem + x) - r, exact reference rounding order, no contraction
    float t = __fmul_rn(0.95f, mem);
    t       = __fadd_rn(t, x);
    mem     = __fsub_rn(t, r);
    r = (mem > 1.0f) ? 1.0f : 0.0f;   // spike_t, doubles as reset_{t+1}
    return r;
}

__global__ __launch_bounds__(64, 1)
void snn_leaky(const float* __restrict__ x, float* __restrict__ out) {
    const int n = blockIdx.x * 64 + threadIdx.x;   // one thread per neuron
    const float4* xr = reinterpret_cast<const float4*>(x   + (size_t)n * T_LEN);
    float4*     orow = reinterpret_cast<float4*>(out + (size_t)n * T_LEN);

    float mem = 0.0f;   // mem_0 = 0
    float r   = 0.0f;   // reset_1 = H(0 - 1) = 0

    float4 A[CHV], B[CHV];

    // Prologue: prefetch chunk 0.
#pragma unroll
    for (int i = 0; i < CHV; ++i) A[i] = xr[i];

    for (int c = 0; c < NCH; c += 2) {
        // Prefetch chunk c+1 while computing chunk c (loads stay in flight;
        // compiler waits vmcnt only before first use of B).
#pragma unroll
        for (int i = 0; i < CHV; ++i) B[i] = xr[(c + 1) * CHV + i];

#pragma unroll
        for (int i = 0; i < CHV; ++i) {
            float4 v = A[i], s;
            s.x = step1(v.x, mem, r);
            s.y = step1(v.y, mem, r);
            s.z = step1(v.z, mem, r);
            s.w = step1(v.w, mem, r);
            orow[c * CHV + i] = s;
        }

        if (c + 2 < NCH) {
#pragma unroll
            for (int i = 0; i < CHV; ++i) A[i] = xr[(c + 2) * CHV + i];
        }

#pragma unroll
        for (int i = 0; i < CHV; ++i) {
            float4 v = B[i], s;
            s.x = step1(v.x, mem, r);
            s.y = step1(v.y, mem, r);
            s.z = step1(v.z, mem, r);
            s.w = step1(v.w, mem, r);
            orow[(c + 1) * CHV + i] = s;
        }
    }
}

} // namespace

extern "C" void kernel_launch(void* const* d_in, const int* in_sizes, int n_in,
                              void* d_out, int out_size, void* d_ws, size_t ws_size,
                              hipStream_t stream) {
    const float* x = (const float*)d_in[0];
    float* out     = (float*)d_out;
    // 8192 neurons, 1 thread each: 128 blocks x 64 threads -> 128 waves spread
    // across >=128 CUs (maximizes per-wave HBM bandwidth share).
    snn_leaky<<<dim3(N_NEU / 64), dim3(64), 0, stream>>>(x, out);
}